// Round 1
// baseline (308.646 us; speedup 1.0000x reference)
//
#include <hip/hip_runtime.h>

// Adder: base-10 digit addition with carry, one wave (64 lanes) per row.
// Row layout: index 0 = most-significant digit, index 63 = least-significant.
// Carry chain solved in closed form via ballot + 64-bit carry-lookahead:
//   g = (s >= 10)  generate, p = (s == 9) propagate  (mutually exclusive)
//   in LSB-first bit order, carry-in bits C = ((P|G)+G) ^ (P|G) ^ G
// Digits are exact small integers in fp32, so float compares are exact.

__global__ __launch_bounds__(256) void adder_kernel(
    const float* __restrict__ a,
    const float* __restrict__ b,
    float* __restrict__ out,
    long long n_rows)
{
    const int lane = (int)(threadIdx.x & 63);
    const long long row = (long long)blockIdx.x * 4 + (threadIdx.x >> 6);
    if (row >= n_rows) return;

    const long long idx = row * 64 + lane;   // wave: 256B contiguous
    const float s = a[idx] + b[idx];         // 0..18, exact integer

    // lane-space masks (bit l = lane l = digit index l; index 63 is LSB)
    const unsigned long long g_l = __ballot(s >= 10.0f);
    const unsigned long long p_l = __ballot(s == 9.0f);

    // reverse into LSB-first position space (position k = 63 - lane)
    const unsigned long long G  = __brevll(g_l);
    const unsigned long long P  = __brevll(p_l);
    const unsigned long long PG = P | G;
    const unsigned long long C_pos = (PG + G) ^ PG ^ G;  // carry-in per position
    const unsigned long long C_l   = __brevll(C_pos);    // back to lane space

    const float cin = (float)((C_l >> lane) & 1ULL);
    const float u = s + cin;                  // 0..19
    const float carry_out = (u >= 10.0f) ? 1.0f : 0.0f;
    out[idx] = u - 10.0f * carry_out;
}

extern "C" void kernel_launch(void* const* d_in, const int* in_sizes, int n_in,
                              void* d_out, int out_size, void* d_ws, size_t ws_size,
                              hipStream_t stream) {
    const float* a = (const float*)d_in[0];
    const float* b = (const float*)d_in[1];
    float* out = (float*)d_out;

    const long long n_rows = (long long)in_sizes[0] / 64;  // 524288
    // 256 threads = 4 waves = 4 rows per block
    const int blocks = (int)((n_rows + 3) / 4);
    adder_kernel<<<blocks, 256, 0, stream>>>(a, b, out, n_rows);
}